// Round 8
// baseline (3035.350 us; speedup 1.0000x reference)
//
#include <hip/hip_runtime.h>
#include <math.h>

#define TT   64
#define BB   2048
#define OBSN 128
#define CTRLN 16
#define LATN 128
#define NMN  16
#define HDN  128

typedef __attribute__((ext_vector_type(8))) short short8;
typedef __attribute__((ext_vector_type(4))) float f32x4;

__device__ __forceinline__ float sigf(float x) { return 1.0f / (1.0f + expf(-x)); }

// fp32 -> bf16 bits, round-to-nearest-even
__device__ __forceinline__ unsigned short f2bf(float x) {
    unsigned int u = __float_as_uint(x);
    unsigned int r = (u + 0x7fffu + ((u >> 16) & 1u)) >> 16;
    return (unsigned short)r;
}

__device__ __forceinline__ f32x4 mfma16(short8 a, short8 b, f32x4 c) {
    return __builtin_amdgcn_mfma_f32_16x16x32_bf16(a, b, c, 0, 0, 0);
}

// ---------------------------------------------------------------------------
// Prep: fp32 -> bf16 bulk convert (vec4)
// ---------------------------------------------------------------------------
__global__ __launch_bounds__(256) void cvt_bf4_k(
    const float* __restrict__ in, unsigned short* __restrict__ out, int n4)
{
    int i = blockIdx.x * 256 + threadIdx.x;
    if (i >= n4) return;
    float4 v = ((const float4*)in)[i];
    ushort4 o;
    o.x = f2bf(v.x); o.y = f2bf(v.y); o.z = f2bf(v.z); o.w = f2bf(v.w);
    ((ushort4*)out)[i] = o;
}

// ---------------------------------------------------------------------------
// Prep: pack W (K x N fp32 row-major) into MFMA B-frag order, K zero-padded
// to KT*32.  out[((nt*KT+kt)*64+lane)*8 + j] = W[kt*32+(lane>>4)*8+j][nt*16+(lane&15)]
// ---------------------------------------------------------------------------
__global__ __launch_bounds__(256) void pack_b_k(
    const float* __restrict__ W, unsigned short* __restrict__ out,
    int K, int N, int KT)
{
    int id = blockIdx.x * 256 + threadIdx.x;
    int total = (N / 16) * KT * 64;
    if (id >= total) return;
    int lane = id & 63;
    int kt = (id >> 6) % KT;
    int nt = id / (64 * KT);
    int n = nt * 16 + (lane & 15);
    int kb = kt * 32 + (lane >> 4) * 8;
#pragma unroll
    for (int j = 0; j < 8; j++) {
        int k = kb + j;
        out[(size_t)id * 8 + j] = (k < K) ? f2bf(W[(size_t)k * N + n]) : (unsigned short)0;
    }
}

// Pack [Wx;Wh] (K=256, N=512, KT=8)
__global__ __launch_bounds__(256) void pack_lstm_k(
    const float* __restrict__ Wx, const float* __restrict__ Wh,
    unsigned short* __restrict__ out)
{
    int id = blockIdx.x * 256 + threadIdx.x;
    if (id >= 32 * 8 * 64) return;
    int lane = id & 63;
    int kt = (id >> 6) & 7;
    int nt = id >> 9;
    int n = nt * 16 + (lane & 15);
    int kb = kt * 32 + (lane >> 4) * 8;
#pragma unroll
    for (int j = 0; j < 8; j++) {
        int k = kb + j;
        float v = (k < 128) ? Wx[(size_t)k * 512 + n] : Wh[(size_t)(k - 128) * 512 + n];
        out[(size_t)id * 8 + j] = f2bf(v);
    }
}

// Pack Wmix: k-rows [A(z):0-127 | Bm(u):128-143 | C(w):144-271 | 0:272-287],
// col c = i*128+j. K=272->KT=9, N=2048.
__global__ __launch_bounds__(256) void pack_wmix_k(
    const float* __restrict__ A, const float* __restrict__ Bm,
    const float* __restrict__ C, unsigned short* __restrict__ out)
{
    int id = blockIdx.x * 256 + threadIdx.x;
    if (id >= 128 * 9 * 64) return;
    int lane = id & 63;
    int kt = (id >> 6) % 9;
    int nt = id / (64 * 9);
    int c = nt * 16 + (lane & 15);
    int i = c >> 7, jj = c & 127;
    int kb = kt * 32 + (lane >> 4) * 8;
#pragma unroll
    for (int j = 0; j < 8; j++) {
        int k = kb + j;
        float v;
        if (k < 128)      v = A[((size_t)(i * 128 + jj)) * 128 + k];
        else if (k < 144) v = Bm[(size_t)(i * 128 + jj) * 16 + (k - 128)];
        else if (k < 272) v = C[(size_t)(i * 128 + jj) * 128 + (k - 144)];
        else              v = 0.f;
        out[(size_t)id * 8 + j] = f2bf(v);
    }
}

// ---------------------------------------------------------------------------
// Persistent LSTM: 128 blocks x 512 threads, 16 batch rows per block,
// 64 time steps in-block.  Weight-resident: 19 frags/wave in registers +
// 13 frags/wave in LDS.  (unchanged from round 3)
// ---------------------------------------------------------------------------
__global__ __launch_bounds__(512, 2) void lstm_k(
    const unsigned short* __restrict__ xs_bf,   // (64,2048,128)
    const unsigned short* __restrict__ lstm_pk, // nt32 x kt8 frag-packed
    const float* __restrict__ bias,             // 512
    float* __restrict__ hlast)                  // (2048,128)
{
    __shared__ unsigned short wl[13 * 8 * 64 * 8];   // 106,496 B
    __shared__ unsigned short h_bf[16][136];
    __shared__ float cs[16][128];
    __shared__ float gb[16][516];
    __shared__ float bs[512];

    const int tid = threadIdx.x;
    const int lane = tid & 63;
    const int w = tid >> 6;          // wave 0..7
    const int quad = lane >> 4;
    const int l15 = lane & 15;
    const int row0 = blockIdx.x * 16;

    // Persistent weight fragments: frag f = s*8+kt (s = n-subtile 0..3, kt 0..7)
    short8 bl[19];
#pragma unroll
    for (int f = 0; f < 19; f++) {
        int s = f >> 3, kt = f & 7;
        bl[f] = *(const short8*)&lstm_pk[((((size_t)(w * 4 + s)) * 8 + kt) * 64 + lane) * 8];
    }
#pragma unroll
    for (int f = 19; f < 32; f++) {
        int s = f >> 3, kt = f & 7;
        *(short8*)&wl[(((size_t)w * 13 + (f - 19)) * 64 + lane) * 8] =
            *(const short8*)&lstm_pk[((((size_t)(w * 4 + s)) * 8 + kt) * 64 + lane) * 8];
    }

    bs[tid] = bias[tid];
    for (int idx = tid; idx < 16 * 136; idx += 512) h_bf[idx / 136][idx % 136] = 0;
    for (int idx = tid; idx < 2048; idx += 512) cs[idx >> 7][idx & 127] = 0.f;

    // prefetch xs for t=0
    short8 axs[4];
#pragma unroll
    for (int kt = 0; kt < 4; kt++)
        axs[kt] = *(const short8*)&xs_bf[((size_t)(row0 + l15)) * 128 + kt * 32 + quad * 8];
    __syncthreads();

    for (int t = 0; t < TT; t++) {
        short8 a[8];
#pragma unroll
        for (int kt = 0; kt < 4; kt++) a[kt] = axs[kt];
#pragma unroll
        for (int kt = 4; kt < 8; kt++)
            a[kt] = *(const short8*)&h_bf[l15][(kt - 4) * 32 + quad * 8];

        f32x4 D[4];
#pragma unroll
        for (int s = 0; s < 4; s++) D[s] = (f32x4){0.f, 0.f, 0.f, 0.f};
#pragma unroll
        for (int s = 0; s < 4; s++) {
#pragma unroll
            for (int kt = 0; kt < 8; kt++) {
                int f = s * 8 + kt;
                short8 b;
                if (f < 19) b = bl[f];
                else        b = *(const short8*)&wl[(((size_t)w * 13 + (f - 19)) * 64 + lane) * 8];
                D[s] = mfma16(a[kt], b, D[s]);
            }
        }
#pragma unroll
        for (int s = 0; s < 4; s++)
#pragma unroll
            for (int rg = 0; rg < 4; rg++)
                gb[quad * 4 + rg][(w * 4 + s) * 16 + l15] = D[s][rg];
        __syncthreads();

        // prefetch next-step xs (consumed after the loop-end barrier)
        if (t + 1 < TT) {
#pragma unroll
            for (int kt = 0; kt < 4; kt++)
                axs[kt] = *(const short8*)&xs_bf[((size_t)(t + 1) * 2048 + row0 + l15) * 128 + kt * 32 + quad * 8];
        }
#pragma unroll
        for (int e = 0; e < 4; e++) {
            int idx = tid + e * 512;
            int r = idx >> 7, j = idx & 127;
            float gi = gb[r][j] + bs[j];
            float gf = gb[r][128 + j] + bs[128 + j];
            float gg = gb[r][256 + j] + bs[256 + j];
            float go = gb[r][384 + j] + bs[384 + j];
            float c = sigf(gf) * cs[r][j] + sigf(gi) * tanhf(gg);
            float h = sigf(go) * tanhf(c);
            cs[r][j] = c;
            h_bf[r][j] = f2bf(h);
            if (t == TT - 1) hlast[(size_t)(row0 + r) * 128 + j] = h;
        }
        __syncthreads();
    }
}

// ---------------------------------------------------------------------------
// Persistent DVBF scan: 128 blocks x 512 threads, 16 rows, 63 steps in-block.
// All 8 waves in every streaming phase.  j-split phase e with z DOUBLE-
// BUFFERED IN LDS: phase e reads A-frags from zb[cur] (loaded inside the
// phase, after the d-barrier) and writes z_{t+1} to zb[cur^1] -> no
// cross-barrier register live ranges (round-7 lesson: scan_k spills past
// 128 VGPRs; cross-barrier frag registers are what pushed it over).
//  - 17/144 wmix frags per wave persisted in LDS (139 KB): per-wave stream
//    144 -> 127 KB/step.
//  - in-lane w-comp: rec2 nt=(w, 8+w): mean+logvar of one column in the
//    same lane; w written straight to amix (no wv buffer, no w-pass).
//  - 5 barriers/step (no part buffer, no reduce phase).
// Buffers: zb[2][16][136] holds z (kt 0-3 of the mix input);
// amix[16][168] holds [u:0-15 | w:16-143 | 0:144-159] (kt 4-8).
// ---------------------------------------------------------------------------
__global__ __launch_bounds__(512, 2) void scan_k(
    const unsigned short* __restrict__ xs_bf,
    const unsigned short* __restrict__ us_bf,
    const float* __restrict__ eps,
    const unsigned short* __restrict__ rec1_pk,  // nt8 kt9
    const float* __restrict__ rec_b1,
    const unsigned short* __restrict__ rec2_pk,  // nt16 kt4
    const float* __restrict__ rec_b2,
    const unsigned short* __restrict__ alpha_pk, // nt1 kt5
    const unsigned short* __restrict__ wmix_pk,  // nt128 kt9
    float* __restrict__ zs)
{
    __shared__ unsigned short zb[2][16][136];    //   8,704 B  z double-buffer
    __shared__ unsigned short amix[16][168];     //   5,376 B  [u|w|pad]
    __shared__ unsigned short rb_bf[16][136];    //   4,352 B
    __shared__ unsigned short wlds[8][17][512];  // 139,264 B  wmix-persist
    __shared__ float logits[16][20];             //   1,280 B
    __shared__ float alph[16][20];               //   1,280 B
    __shared__ float b1s[128];                   //     512 B
    __shared__ float b2s[256];                   //   1,024 B
    // total 161,792 B -> 1 block/CU

    const int tid = threadIdx.x;
    const int lane = tid & 63;
    const int w = tid >> 6;
    const int quad = lane >> 4;
    const int l15 = lane & 15;
    const int row0 = blockIdx.x * 16;

    // persistent register fragments (round-3-proven 88-VGPR budget):
    // rec1 (nt = w), rec2 (nt = w and 8+w), alpha (wave 7)
    short8 r1f[9];
#pragma unroll
    for (int kt = 0; kt < 9; kt++)
        r1f[kt] = *(const short8*)&rec1_pk[(((size_t)w * 9 + kt) * 64 + lane) * 8];
    short8 r2f[8];
#pragma unroll
    for (int kt = 0; kt < 4; kt++) {
        r2f[kt]     = *(const short8*)&rec2_pk[((((size_t)w) * 4 + kt) * 64 + lane) * 8];
        r2f[4 + kt] = *(const short8*)&rec2_pk[((((size_t)(8 + w)) * 4 + kt) * 64 + lane) * 8];
    }
    short8 alf[5];
#pragma unroll
    for (int kt = 0; kt < 5; kt++)
        alf[kt] = *(const short8*)&alpha_pk[((size_t)kt * 64 + lane) * 8];

    // LDS-persist 17 wmix frags for this wave's j-tile (jt = w):
    // f<9 -> (i=0, kt=f);  f>=9 -> (i=1, kt=f-9)
#pragma unroll
    for (int f = 0; f < 17; f++) {
        int i = (f < 9) ? 0 : 1;
        int kt = (f < 9) ? f : f - 9;
        *(short8*)&wlds[w][f][lane * 8] =
            *(const short8*)&wmix_pk[((((size_t)i * 8 + w) * 9 + kt) * 64 + lane) * 8];
    }

    if (tid < 128) b1s[tid] = rec_b1[tid];
    if (tid < 256) b2s[tid] = rec_b2[tid];
    // zero amix pad cols 144-159 (NaN guard: wmix k-rows 272-287 are zero,
    // but 0 * NaN = NaN, so the A operand must be finite)
    for (int idx = tid; idx < 256; idx += 512)
        amix[idx >> 4][144 + (idx & 15)] = 0;
    // z_1 -> zb[0]
    for (int idx = tid; idx < 2048; idx += 512) {
        int r = idx >> 7, j = idx & 127;
        zb[0][r][j] = f2bf(zs[(size_t)(row0 + r) * 128 + j]);
    }
    __syncthreads();

    float ge[4];
    short8 axs[4];
    int cur = 0;

    for (int t = 0; t < TT - 1; t++) {
        // phase a: stage u_t into amix cols 0-15; prefetch eps[t] (own cols,
        // used in c) and xs[t+1] (used in b)
        if (tid < 256) {
            int r = tid >> 4, c = tid & 15;
            amix[r][c] = us_bf[((size_t)t * 2048 + row0 + r) * 16 + c];
        }
#pragma unroll
        for (int rg = 0; rg < 4; rg++)
            ge[rg] = eps[((size_t)t * 2048 + row0 + quad * 4 + rg) * 128 + w * 16 + l15];
#pragma unroll
        for (int kt = 0; kt < 4; kt++)
            axs[kt] = *(const short8*)&xs_bf[((size_t)(t + 1) * 2048 + row0 + l15) * 128 + kt * 32 + quad * 8];
        __syncthreads();

        // phase b: rec1  r = relu([z|x_{t+1}|u] @ W1 + b1); wave w -> n-tile w
        {
            short8 a[9];
#pragma unroll
            for (int kt = 0; kt < 4; kt++)
                a[kt] = *(const short8*)&zb[cur][l15][kt * 32 + quad * 8];
#pragma unroll
            for (int kt = 4; kt < 8; kt++) a[kt] = axs[kt - 4];
            {
                short8 zz = {0, 0, 0, 0, 0, 0, 0, 0};
                a[8] = (quad < 2) ? *(const short8*)&amix[l15][quad * 8] : zz;
            }
            f32x4 D = {0.f, 0.f, 0.f, 0.f};
#pragma unroll
            for (int kt = 0; kt < 9; kt++)
                D = mfma16(a[kt], r1f[kt], D);
            int col = w * 16 + l15;
#pragma unroll
            for (int rg = 0; rg < 4; rg++) {
                float v = fmaxf(D[rg] + b1s[col], 0.f);
                rb_bf[quad * 4 + rg][col] = f2bf(v);
            }
        }
        __syncthreads();

        // phase c: rec2 mean (nt=w) + logvar (nt=8+w) in-lane -> w into amix
        // cols 16-143; alpha logits (wave 7)
        {
            short8 a2[4];
#pragma unroll
            for (int kt = 0; kt < 4; kt++)
                a2[kt] = *(const short8*)&rb_bf[l15][kt * 32 + quad * 8];
            f32x4 Dm = {0.f, 0.f, 0.f, 0.f}, Dl = {0.f, 0.f, 0.f, 0.f};
#pragma unroll
            for (int kt = 0; kt < 4; kt++) {
                Dm = mfma16(a2[kt], r2f[kt], Dm);
                Dl = mfma16(a2[kt], r2f[4 + kt], Dl);
            }
            int col = w * 16 + l15;
#pragma unroll
            for (int rg = 0; rg < 4; rg++) {
                float mv = Dm[rg] + b2s[col];
                float lv = Dl[rg] + b2s[128 + col];
                float wval = mv + expf(0.5f * lv) * ge[rg];
                amix[quad * 4 + rg][16 + col] = f2bf(wval);
            }
            if (w == 7) {
                short8 az[5];
#pragma unroll
                for (int kt = 0; kt < 4; kt++)
                    az[kt] = *(const short8*)&zb[cur][l15][kt * 32 + quad * 8];
                short8 zz = {0, 0, 0, 0, 0, 0, 0, 0};
                az[4] = (quad < 2) ? *(const short8*)&amix[l15][quad * 8] : zz;
                f32x4 DL = {0.f, 0.f, 0.f, 0.f};
#pragma unroll
                for (int kt = 0; kt < 5; kt++)
                    DL = mfma16(az[kt], alf[kt], DL);
#pragma unroll
                for (int rg = 0; rg < 4; rg++)
                    logits[quad * 4 + rg][l15] = DL[rg];
            }
        }
        __syncthreads();

        // phase d: wave-parallel softmax only (16 rows x 16 i on 256 threads)
        if (tid < 256) {
            int r = tid >> 4, i = tid & 15;
            float x = logits[r][i];
            float m = x;
#pragma unroll
            for (int off = 8; off > 0; off >>= 1)
                m = fmaxf(m, __shfl_xor(m, off, 16));
            float e = expf(x - m);
            float s = e;
#pragma unroll
            for (int off = 8; off > 0; off >>= 1)
                s += __shfl_xor(s, off, 16);
            alph[r][i] = e / s;
        }
        __syncthreads();

        // phase e: j-split mix GEMM. wave w owns cols [16w,16w+16); loops
        // all 16 i; alpha folded per-i.  A-frags loaded HERE (kt0-3 from
        // zb[cur], kt4-8 from amix) -- no cross-barrier registers.  z_{t+1}
        // written to zb[cur^1] (never read this step) + zs.
        {
            short8 am[9];
#pragma unroll
            for (int kt = 0; kt < 4; kt++)
                am[kt] = *(const short8*)&zb[cur][l15][kt * 32 + quad * 8];
#pragma unroll
            for (int kt = 4; kt < 9; kt++)
                am[kt] = *(const short8*)&amix[l15][(kt - 4) * 32 + quad * 8];
            f32x4 acc = {0.f, 0.f, 0.f, 0.f};
#pragma unroll
            for (int i = 0; i < 16; i++) {
                f32x4 D = {0.f, 0.f, 0.f, 0.f};
#pragma unroll
                for (int kt = 0; kt < 9; kt++) {
                    short8 b;
                    if (i * 9 + kt < 17)
                        b = *(const short8*)&wlds[w][i * 9 + kt][lane * 8];
                    else
                        b = *(const short8*)&wmix_pk[((((size_t)i * 8 + w) * 9 + kt) * 64 + lane) * 8];
                    D = mfma16(am[kt], b, D);
                }
#pragma unroll
                for (int rg = 0; rg < 4; rg++)
                    acc[rg] += alph[quad * 4 + rg][i] * D[rg];
            }
#pragma unroll
            for (int rg = 0; rg < 4; rg++) {
                int r = quad * 4 + rg;
                float z = acc[rg];
                zs[((size_t)(t + 1) * 2048 + row0 + r) * 128 + w * 16 + l15] = z;
                zb[cur ^ 1][r][w * 16 + l15] = f2bf(z);
            }
        }
        __syncthreads();
        cur ^= 1;
    }
}

// ---------------------------------------------------------------------------
// fp32 helper GEMMs for the small init-network tail (unchanged)
// ---------------------------------------------------------------------------
template <int RELU>
__global__ __launch_bounds__(256) void gemm_bias_k(
    const float* __restrict__ A, const float* __restrict__ W,
    const float* __restrict__ bias, float* __restrict__ Cout,
    int M, int K, int N)
{
    __shared__ float As[16][68];
    __shared__ float Ws[16][64];
    const int tid = threadIdx.x;
    const int row0 = blockIdx.x * 64;
    const int col0 = blockIdx.y * 64;
    const int tx = tid & 15, ty = tid >> 4;
    float acc[4][4];
#pragma unroll
    for (int a = 0; a < 4; a++)
#pragma unroll
        for (int b = 0; b < 4; b++) acc[a][b] = 0.f;

    for (int kc = 0; kc < K; kc += 16) {
        __syncthreads();
#pragma unroll
        for (int e = 0; e < 4; e++) {
            int idx = tid + e * 256;
            int r = idx >> 4, kk = idx & 15;
            As[kk][r] = A[(size_t)(row0 + r) * K + kc + kk];
        }
#pragma unroll
        for (int e = 0; e < 4; e++) {
            int idx = tid + e * 256;
            int kk = idx >> 6, jj = idx & 63;
            Ws[kk][jj] = W[(kc + kk) * N + col0 + jj];
        }
        __syncthreads();
#pragma unroll
        for (int kk = 0; kk < 16; kk++) {
            const float4 a4 = *(const float4*)&As[kk][ty * 4];
            const float4 w4 = *(const float4*)&Ws[kk][tx * 4];
            const float av[4] = {a4.x, a4.y, a4.z, a4.w};
            const float wv2[4] = {w4.x, w4.y, w4.z, w4.w};
#pragma unroll
            for (int r = 0; r < 4; r++)
#pragma unroll
                for (int j = 0; j < 4; j++) acc[r][j] += av[r] * wv2[j];
        }
    }
#pragma unroll
    for (int r = 0; r < 4; r++)
#pragma unroll
        for (int j = 0; j < 4; j++) {
            int gr = row0 + ty * 4 + r, gc = col0 + tx * 4 + j;
            float v = acc[r][j] + bias[gc];
            if (RELU) v = fmaxf(v, 0.f);
            Cout[(size_t)gr * N + gc] = v;
        }
}

__global__ __launch_bounds__(256) void gemm_meanvar_k(
    const float* __restrict__ A, const float* __restrict__ W,
    const float* __restrict__ bias, const float* __restrict__ eps,
    float* __restrict__ out)
{
    __shared__ float As[16][36];
    __shared__ float Ws[16][128];
    const int tid = threadIdx.x;
    const int row0 = blockIdx.x * 32;
    const int j0 = blockIdx.y * 64;
    const int tjx = tid & 31;
    const int trg = tid >> 5;
    float am[4][2], al[4][2];
#pragma unroll
    for (int a = 0; a < 4; a++) { am[a][0] = am[a][1] = 0.f; al[a][0] = al[a][1] = 0.f; }

    for (int kc = 0; kc < 128; kc += 16) {
        __syncthreads();
#pragma unroll
        for (int e = 0; e < 2; e++) {
            int idx = tid + e * 256;
            int r = idx >> 4, kk = idx & 15;
            As[kk][r] = A[(row0 + r) * 128 + kc + kk];
        }
#pragma unroll
        for (int e = 0; e < 2; e++) {
            int idx = tid + e * 256;
            int lin = idx * 4;
            int kk = lin >> 7, cc = lin & 127;
            int half = cc >> 6, jj = cc & 63;
            *(float4*)&Ws[kk][half * 64 + jj] =
                *(const float4*)(W + (kc + kk) * 256 + half * 128 + j0 + jj);
        }
        __syncthreads();
#pragma unroll
        for (int kk = 0; kk < 16; kk++) {
            const float4 a4 = *(const float4*)&As[kk][trg * 4];
            const float2 wm = *(const float2*)&Ws[kk][2 * tjx];
            const float2 wl = *(const float2*)&Ws[kk][64 + 2 * tjx];
            const float av[4] = {a4.x, a4.y, a4.z, a4.w};
#pragma unroll
            for (int rr = 0; rr < 4; rr++) {
                am[rr][0] += av[rr] * wm.x; am[rr][1] += av[rr] * wm.y;
                al[rr][0] += av[rr] * wl.x; al[rr][1] += av[rr] * wl.y;
            }
        }
    }
#pragma unroll
    for (int rr = 0; rr < 4; rr++)
#pragma unroll
        for (int jj = 0; jj < 2; jj++) {
            int r = row0 + trg * 4 + rr;
            int j = j0 + 2 * tjx + jj;
            float m = am[rr][jj] + bias[j];
            float l = al[rr][jj] + bias[128 + j];
            out[r * 128 + j] = m + expf(0.5f * l) * eps[r * 128 + j];
        }
}

// ---------------------------------------------------------------------------
// Fused 2-layer MLP for x_rec (fp32, unchanged)
// ---------------------------------------------------------------------------
__global__ __launch_bounds__(256) void mlp2_k(
    const float* __restrict__ Z, const float* __restrict__ W1,
    const float* __restrict__ b1, const float* __restrict__ W2,
    const float* __restrict__ b2, float* __restrict__ out)
{
    __shared__ float Zs[32][132];
    __shared__ float Hs[32][132];
    __shared__ float Ws[16][128];
    const int tid = threadIdx.x;
    const int row0 = blockIdx.x * 32;
    const int tx = tid & 31;
    const int ty = tid >> 5;

#pragma unroll
    for (int e = 0; e < 4; e++) {
        int idx = tid + e * 256;
        int lin = idx * 4;
        int r = lin >> 7, k = lin & 127;
        *(float4*)&Zs[r][k] = *(const float4*)(Z + (size_t)(row0 + r) * 128 + k);
    }

    float acc[4][4];
#pragma unroll
    for (int a = 0; a < 4; a++)
#pragma unroll
        for (int b = 0; b < 4; b++) acc[a][b] = 0.f;

    for (int kc = 0; kc < 128; kc += 16) {
        __syncthreads();
#pragma unroll
        for (int e = 0; e < 2; e++) {
            int idx = tid + e * 256;
            int lin = idx * 4;
            int kk = lin >> 7, j = lin & 127;
            *(float4*)&Ws[kk][j] = *(const float4*)(W1 + (kc + kk) * 128 + j);
        }
        __syncthreads();
#pragma unroll
        for (int kk = 0; kk < 16; kk++) {
            float av[4];
#pragma unroll
            for (int rr = 0; rr < 4; rr++) av[rr] = Zs[ty * 4 + rr][kc + kk];
            const float4 w4 = *(const float4*)&Ws[kk][tx * 4];
            const float wv2[4] = {w4.x, w4.y, w4.z, w4.w};
#pragma unroll
            for (int r = 0; r < 4; r++)
#pragma unroll
                for (int j = 0; j < 4; j++) acc[r][j] += av[r] * wv2[j];
        }
    }
#pragma unroll
    for (int rr = 0; rr < 4; rr++) {
        float4 hv;
        hv.x = fmaxf(acc[rr][0] + b1[tx * 4 + 0], 0.f);
        hv.y = fmaxf(acc[rr][1] + b1[tx * 4 + 1], 0.f);
        hv.z = fmaxf(acc[rr][2] + b1[tx * 4 + 2], 0.f);
        hv.w = fmaxf(acc[rr][3] + b1[tx * 4 + 3], 0.f);
        *(float4*)&Hs[ty * 4 + rr][tx * 4] = hv;
    }
#pragma unroll
    for (int a = 0; a < 4; a++)
#pragma unroll
        for (int b = 0; b < 4; b++) acc[a][b] = 0.f;

    for (int kc = 0; kc < 128; kc += 16) {
        __syncthreads();
#pragma unroll
        for (int e = 0; e < 2; e++) {
            int idx = tid + e * 256;
            int lin = idx * 4;
            int kk = lin >> 7, j = lin & 127;
            *(float4*)&Ws[kk][j] = *(const float4*)(W2 + (kc + kk) * 128 + j);
        }
        __syncthreads();
#pragma unroll
        for (int kk = 0; kk < 16; kk++) {
            float av[4];
#pragma unroll
            for (int rr = 0; rr < 4; rr++) av[rr] = Hs[ty * 4 + rr][kc + kk];
            const float4 w4 = *(const float4*)&Ws[kk][tx * 4];
            const float wv2[4] = {w4.x, w4.y, w4.z, w4.w};
#pragma unroll
            for (int r = 0; r < 4; r++)
#pragma unroll
                for (int j = 0; j < 4; j++) acc[r][j] += av[r] * wv2[j];
        }
    }
#pragma unroll
    for (int rr = 0; rr < 4; rr++) {
        float4 ov;
        ov.x = acc[rr][0] + b2[tx * 4 + 0];
        ov.y = acc[rr][1] + b2[tx * 4 + 1];
        ov.z = acc[rr][2] + b2[tx * 4 + 2];
        ov.w = acc[rr][3] + b2[tx * 4 + 3];
        *(float4*)(out + (size_t)(row0 + ty * 4 + rr) * 128 + tx * 4) = ov;
    }
}

// ---------------------------------------------------------------------------
extern "C" void kernel_launch(void* const* d_in, const int* in_sizes, int n_in,
                              void* d_out, int out_size, void* d_ws, size_t ws_size,
                              hipStream_t stream)
{
    (void)in_sizes; (void)n_in; (void)out_size; (void)ws_size;
    const float* xs       = (const float*)d_in[0];
    const float* us       = (const float*)d_in[1];
    const float* eps1     = (const float*)d_in[2];
    const float* eps      = (const float*)d_in[3];
    const float* lstm_Wx  = (const float*)d_in[4];
    const float* lstm_Wh  = (const float*)d_in[5];
    const float* lstm_b   = (const float*)d_in[6];
    const float* init_W1  = (const float*)d_in[7];
    const float* init_b1  = (const float*)d_in[8];
    const float* init_W2  = (const float*)d_in[9];
    const float* init_b2  = (const float*)d_in[10];
    const float* trans_W1 = (const float*)d_in[11];
    const float* trans_b1 = (const float*)d_in[12];
    const float* trans_W2 = (const float*)d_in[13];
    const float* trans_b2 = (const float*)d_in[14];
    const float* obs_W1   = (const float*)d_in[15];
    const float* obs_b1   = (const float*)d_in[16];
    const float* obs_W2   = (const float*)d_in[17];
    const float* obs_b2   = (const float*)d_in[18];
    const float* rec_W1   = (const float*)d_in[19];
    const float* rec_b1   = (const float*)d_in[20];
    const float* rec_W2   = (const float*)d_in[21];
    const float* rec_b2   = (const float*)d_in[22];
    const float* alpha_W  = (const float*)d_in[23];
    const float* Amat     = (const float*)d_in[24];
    const float* Bmat     = (const float*)d_in[25];
    const float* Cmat     = (const float*)d_in[26];

    float* out  = (float*)d_out;
    float* zs   = out;                           // (64*2048, 128)
    float* xrec = out + (size_t)TT * BB * LATN;  // (63*2048, 128)

    // workspace layout (bytes)
    char* ws = (char*)d_ws;
    unsigned short* xs_bf   = (unsigned short*)(ws);                    // 33,554,432 B
    unsigned short* us_bf   = (unsigned short*)(ws + 33554432);         //  4,194,304 B
    unsigned short* lstm_pk = (unsigned short*)(ws + 37748736);         //    262,144 B
    unsigned short* rec1_pk = (unsigned short*)(ws + 38010880);         //     73,728 B
    unsigned short* rec2_pk = (unsigned short*)(ws + 38084608);         //     65,536 B
    unsigned short* alpha_pk= (unsigned short*)(ws + 38150144);         //      5,120 B
    unsigned short* wmix_pk = (unsigned short*)(ws + 38155264);         //  1,179,648 B
    float* hlast            = (float*)(ws + 39334912);                  //  1,048,576 B
    float* hidb             = (float*)(ws + 40383488);
    float* w1b              = (float*)(ws + 41432064);
    float* rbg              = (float*)(ws + 42480640);                  // ends 43,529,216

    // ---- prep ----
    cvt_bf4_k<<<16384, 256, 0, stream>>>(xs, xs_bf, 4194304);
    cvt_bf4_k<<<2048, 256, 0, stream>>>(us, us_bf, 524288);
    pack_lstm_k<<<64, 256, 0, stream>>>(lstm_Wx, lstm_Wh, lstm_pk);
    pack_b_k<<<18, 256, 0, stream>>>(rec_W1, rec1_pk, 272, 128, 9);
    pack_b_k<<<16, 256, 0, stream>>>(rec_W2, rec2_pk, 128, 256, 4);
    pack_b_k<<<2, 256, 0, stream>>>(alpha_W, alpha_pk, 144, 16, 5);
    pack_wmix_k<<<288, 256, 0, stream>>>(Amat, Bmat, Cmat, wmix_pk);

    // ---- LSTM (persistent, weight-resident) ----
    lstm_k<<<128, 512, 0, stream>>>(xs_bf, lstm_pk, lstm_b, hlast);

    // ---- init-network tail + initial transition (fp32) ----
    gemm_bias_k<1><<<dim3(32, 2), 256, 0, stream>>>(hlast, init_W1, init_b1, hidb, BB, 128, 128);
    gemm_meanvar_k<<<dim3(64, 2), 256, 0, stream>>>(hidb, init_W2, init_b2, eps1, w1b);
    gemm_bias_k<1><<<dim3(32, 2), 256, 0, stream>>>(w1b, trans_W1, trans_b1, rbg, BB, 128, 128);
    gemm_bias_k<0><<<dim3(32, 2), 256, 0, stream>>>(rbg, trans_W2, trans_b2, zs, BB, 128, 128);

    // ---- DVBF scan (j-split mix, LDS z double-buffer, LDS weight-persist) ----
    scan_k<<<128, 512, 0, stream>>>(xs_bf, us_bf, eps,
                                    rec1_pk, rec_b1, rec2_pk, rec_b2,
                                    alpha_pk, wmix_pk, zs);

    // ---- x_rec = obs_fn(zs[0..62]) ----
    mlp2_k<<<dim3((TT - 1) * BB / 32), 256, 0, stream>>>(
        zs, obs_W1, obs_b1, obs_W2, obs_b2, xrec);
}

// Round 9
// 1327.979 us; speedup vs baseline: 2.2857x; 2.2857x over previous
//
#include <hip/hip_runtime.h>
#include <math.h>

#define TT   64
#define BB   2048
#define OBSN 128
#define CTRLN 16
#define LATN 128
#define NMN  16
#define HDN  128

typedef __attribute__((ext_vector_type(8))) short short8;
typedef __attribute__((ext_vector_type(4))) float f32x4;

__device__ __forceinline__ float sigf(float x) { return 1.0f / (1.0f + expf(-x)); }

// fp32 -> bf16 bits, round-to-nearest-even
__device__ __forceinline__ unsigned short f2bf(float x) {
    unsigned int u = __float_as_uint(x);
    unsigned int r = (u + 0x7fffu + ((u >> 16) & 1u)) >> 16;
    return (unsigned short)r;
}

__device__ __forceinline__ f32x4 mfma16(short8 a, short8 b, f32x4 c) {
    return __builtin_amdgcn_mfma_f32_16x16x32_bf16(a, b, c, 0, 0, 0);
}

// ---------------------------------------------------------------------------
// Prep: fp32 -> bf16 bulk convert (vec4)
// ---------------------------------------------------------------------------
__global__ __launch_bounds__(256) void cvt_bf4_k(
    const float* __restrict__ in, unsigned short* __restrict__ out, int n4)
{
    int i = blockIdx.x * 256 + threadIdx.x;
    if (i >= n4) return;
    float4 v = ((const float4*)in)[i];
    ushort4 o;
    o.x = f2bf(v.x); o.y = f2bf(v.y); o.z = f2bf(v.z); o.w = f2bf(v.w);
    ((ushort4*)out)[i] = o;
}

// ---------------------------------------------------------------------------
// Prep: pack W (K x N fp32 row-major) into MFMA B-frag order, K zero-padded
// to KT*32.  out[((nt*KT+kt)*64+lane)*8 + j] = W[kt*32+(lane>>4)*8+j][nt*16+(lane&15)]
// ---------------------------------------------------------------------------
__global__ __launch_bounds__(256) void pack_b_k(
    const float* __restrict__ W, unsigned short* __restrict__ out,
    int K, int N, int KT)
{
    int id = blockIdx.x * 256 + threadIdx.x;
    int total = (N / 16) * KT * 64;
    if (id >= total) return;
    int lane = id & 63;
    int kt = (id >> 6) % KT;
    int nt = id / (64 * KT);
    int n = nt * 16 + (lane & 15);
    int kb = kt * 32 + (lane >> 4) * 8;
#pragma unroll
    for (int j = 0; j < 8; j++) {
        int k = kb + j;
        out[(size_t)id * 8 + j] = (k < K) ? f2bf(W[(size_t)k * N + n]) : (unsigned short)0;
    }
}

// Pack [Wx;Wh] (K=256, N=512, KT=8)
__global__ __launch_bounds__(256) void pack_lstm_k(
    const float* __restrict__ Wx, const float* __restrict__ Wh,
    unsigned short* __restrict__ out)
{
    int id = blockIdx.x * 256 + threadIdx.x;
    if (id >= 32 * 8 * 64) return;
    int lane = id & 63;
    int kt = (id >> 6) & 7;
    int nt = id >> 9;
    int n = nt * 16 + (lane & 15);
    int kb = kt * 32 + (lane >> 4) * 8;
#pragma unroll
    for (int j = 0; j < 8; j++) {
        int k = kb + j;
        float v = (k < 128) ? Wx[(size_t)k * 512 + n] : Wh[(size_t)(k - 128) * 512 + n];
        out[(size_t)id * 8 + j] = f2bf(v);
    }
}

// Pack Wmix: k-rows [A(z):0-127 | Bm(u):128-143 | C(w):144-271 | 0:272-287],
// col c = i*128+j. K=272->KT=9, N=2048.
__global__ __launch_bounds__(256) void pack_wmix_k(
    const float* __restrict__ A, const float* __restrict__ Bm,
    const float* __restrict__ C, unsigned short* __restrict__ out)
{
    int id = blockIdx.x * 256 + threadIdx.x;
    if (id >= 128 * 9 * 64) return;
    int lane = id & 63;
    int kt = (id >> 6) % 9;
    int nt = id / (64 * 9);
    int c = nt * 16 + (lane & 15);
    int i = c >> 7, jj = c & 127;
    int kb = kt * 32 + (lane >> 4) * 8;
#pragma unroll
    for (int j = 0; j < 8; j++) {
        int k = kb + j;
        float v;
        if (k < 128)      v = A[((size_t)(i * 128 + jj)) * 128 + k];
        else if (k < 144) v = Bm[(size_t)(i * 128 + jj) * 16 + (k - 128)];
        else if (k < 272) v = C[(size_t)(i * 128 + jj) * 128 + (k - 144)];
        else              v = 0.f;
        out[(size_t)id * 8 + j] = f2bf(v);
    }
}

// ---------------------------------------------------------------------------
// Persistent LSTM: 128 blocks x 512 threads, 16 batch rows per block,
// 64 time steps in-block.  Weight-resident: 19 frags/wave in registers +
// 13 frags/wave in LDS.  (unchanged from round 3)
// ---------------------------------------------------------------------------
__global__ __launch_bounds__(512, 2) void lstm_k(
    const unsigned short* __restrict__ xs_bf,   // (64,2048,128)
    const unsigned short* __restrict__ lstm_pk, // nt32 x kt8 frag-packed
    const float* __restrict__ bias,             // 512
    float* __restrict__ hlast)                  // (2048,128)
{
    __shared__ unsigned short wl[13 * 8 * 64 * 8];   // 106,496 B
    __shared__ unsigned short h_bf[16][136];
    __shared__ float cs[16][128];
    __shared__ float gb[16][516];
    __shared__ float bs[512];

    const int tid = threadIdx.x;
    const int lane = tid & 63;
    const int w = tid >> 6;          // wave 0..7
    const int quad = lane >> 4;
    const int l15 = lane & 15;
    const int row0 = blockIdx.x * 16;

    // Persistent weight fragments: frag f = s*8+kt (s = n-subtile 0..3, kt 0..7)
    short8 bl[19];
#pragma unroll
    for (int f = 0; f < 19; f++) {
        int s = f >> 3, kt = f & 7;
        bl[f] = *(const short8*)&lstm_pk[((((size_t)(w * 4 + s)) * 8 + kt) * 64 + lane) * 8];
    }
#pragma unroll
    for (int f = 19; f < 32; f++) {
        int s = f >> 3, kt = f & 7;
        *(short8*)&wl[(((size_t)w * 13 + (f - 19)) * 64 + lane) * 8] =
            *(const short8*)&lstm_pk[((((size_t)(w * 4 + s)) * 8 + kt) * 64 + lane) * 8];
    }

    bs[tid] = bias[tid];
    for (int idx = tid; idx < 16 * 136; idx += 512) h_bf[idx / 136][idx % 136] = 0;
    for (int idx = tid; idx < 2048; idx += 512) cs[idx >> 7][idx & 127] = 0.f;

    // prefetch xs for t=0
    short8 axs[4];
#pragma unroll
    for (int kt = 0; kt < 4; kt++)
        axs[kt] = *(const short8*)&xs_bf[((size_t)(row0 + l15)) * 128 + kt * 32 + quad * 8];
    __syncthreads();

    for (int t = 0; t < TT; t++) {
        short8 a[8];
#pragma unroll
        for (int kt = 0; kt < 4; kt++) a[kt] = axs[kt];
#pragma unroll
        for (int kt = 4; kt < 8; kt++)
            a[kt] = *(const short8*)&h_bf[l15][(kt - 4) * 32 + quad * 8];

        f32x4 D[4];
#pragma unroll
        for (int s = 0; s < 4; s++) D[s] = (f32x4){0.f, 0.f, 0.f, 0.f};
#pragma unroll
        for (int s = 0; s < 4; s++) {
#pragma unroll
            for (int kt = 0; kt < 8; kt++) {
                int f = s * 8 + kt;
                short8 b;
                if (f < 19) b = bl[f];
                else        b = *(const short8*)&wl[(((size_t)w * 13 + (f - 19)) * 64 + lane) * 8];
                D[s] = mfma16(a[kt], b, D[s]);
            }
        }
#pragma unroll
        for (int s = 0; s < 4; s++)
#pragma unroll
            for (int rg = 0; rg < 4; rg++)
                gb[quad * 4 + rg][(w * 4 + s) * 16 + l15] = D[s][rg];
        __syncthreads();

        // prefetch next-step xs (consumed after the loop-end barrier)
        if (t + 1 < TT) {
#pragma unroll
            for (int kt = 0; kt < 4; kt++)
                axs[kt] = *(const short8*)&xs_bf[((size_t)(t + 1) * 2048 + row0 + l15) * 128 + kt * 32 + quad * 8];
        }
#pragma unroll
        for (int e = 0; e < 4; e++) {
            int idx = tid + e * 512;
            int r = idx >> 7, j = idx & 127;
            float gi = gb[r][j] + bs[j];
            float gf = gb[r][128 + j] + bs[128 + j];
            float gg = gb[r][256 + j] + bs[256 + j];
            float go = gb[r][384 + j] + bs[384 + j];
            float c = sigf(gf) * cs[r][j] + sigf(gi) * tanhf(gg);
            float h = sigf(go) * tanhf(c);
            cs[r][j] = c;
            h_bf[r][j] = f2bf(h);
            if (t == TT - 1) hlast[(size_t)(row0 + r) * 128 + j] = h;
        }
        __syncthreads();
    }
}

// ---------------------------------------------------------------------------
// Persistent DVBF scan: 128 blocks x 512 threads, 16 rows, 63 steps in-block.
// EXACT round-3 structure (i-split phase e, part buffer + reduce, 6 barriers,
// #pragma unroll 1 on the jt loop -- the only phase-e shape that allocates
// under the hard 128-VGPR cap; rounds 6-8's j-split/full-unroll all spilled).
// Register-neutral deltas only:
//  - in-lane w-comp: rec2 nt=(w, 8+w) puts mean+logvar of one column in the
//    same lane; w computed in phase c, written straight to amix.  wv buffer
//    (16.6 KB) and phase-d w-pass deleted.  Same register count as round 3.
//  - 8/144 wmix frags per wave LDS-persisted (wlds, 64 KB): kt=0 of i0=2w
//    for all jt.  Select is on kt (compile-time) inside the runtime-jt loop
//    -- no forced unroll, zero new registers.  Stream 144 -> 136 KB/wave.
// amix layout per row: [z:0-127 | u:128-143 | w:144-271 | 0:272-287]
// ---------------------------------------------------------------------------
__global__ __launch_bounds__(512, 2) void scan_k(
    const unsigned short* __restrict__ xs_bf,
    const unsigned short* __restrict__ us_bf,
    const float* __restrict__ eps,
    const unsigned short* __restrict__ rec1_pk,  // nt8 kt9
    const float* __restrict__ rec_b1,
    const unsigned short* __restrict__ rec2_pk,  // nt16 kt4
    const float* __restrict__ rec_b2,
    const unsigned short* __restrict__ alpha_pk, // nt1 kt5
    const unsigned short* __restrict__ wmix_pk,  // nt128 kt9
    float* __restrict__ zs)
{
    __shared__ unsigned short amix[16][296];     //   9,472 B
    __shared__ unsigned short rb_bf[16][136];    //   4,352 B
    __shared__ unsigned short wlds[8][8][512];   //  65,536 B  (i0, jt, kt=0)
    __shared__ float part[8][16][132];           //  67,584 B
    __shared__ float logits[16][20];             //   1,280 B
    __shared__ float alph[16][20];               //   1,280 B
    __shared__ float b1s[128];                   //     512 B
    __shared__ float b2s[256];                   //   1,024 B
    // total 151,040 B -> 1 block/CU

    const int tid = threadIdx.x;
    const int lane = tid & 63;
    const int w = tid >> 6;
    const int quad = lane >> 4;
    const int l15 = lane & 15;
    const int row0 = blockIdx.x * 16;
    const int i0 = 2 * w, i1 = 2 * w + 1;

    // persistent register fragments (round-3-proven 88-VGPR budget):
    // rec1 (nt = w), rec2 (nt = w and 8+w), alpha (used by wave 7)
    short8 r1f[9];
#pragma unroll
    for (int kt = 0; kt < 9; kt++)
        r1f[kt] = *(const short8*)&rec1_pk[(((size_t)w * 9 + kt) * 64 + lane) * 8];
    short8 r2f[8];
#pragma unroll
    for (int kt = 0; kt < 4; kt++) {
        r2f[kt]     = *(const short8*)&rec2_pk[((((size_t)w) * 4 + kt) * 64 + lane) * 8];
        r2f[4 + kt] = *(const short8*)&rec2_pk[((((size_t)(8 + w)) * 4 + kt) * 64 + lane) * 8];
    }
    short8 alf[5];
#pragma unroll
    for (int kt = 0; kt < 5; kt++)
        alf[kt] = *(const short8*)&alpha_pk[((size_t)kt * 64 + lane) * 8];

    // LDS-persist kt=0 frags of i0 for all jt (wave-private; read-only after)
#pragma unroll
    for (int jt = 0; jt < 8; jt++)
        *(short8*)&wlds[w][jt][lane * 8] =
            *(const short8*)&wmix_pk[((((size_t)i0 * 8 + jt) * 9 + 0) * 64 + lane) * 8];

    if (tid < 128) b1s[tid] = rec_b1[tid];
    if (tid < 256) b2s[tid] = rec_b2[tid];
    for (int idx = tid; idx < 256; idx += 512)
        amix[idx >> 4][272 + (idx & 15)] = 0;
    for (int idx = tid; idx < 2048; idx += 512) {
        int r = idx >> 7, j = idx & 127;
        amix[r][j] = f2bf(zs[(size_t)(row0 + r) * 128 + j]);
    }
    __syncthreads();

    float ge[4];
    short8 axs[4];

    for (int t = 0; t < TT - 1; t++) {
        // phase a: stage u_t into amix; prefetch eps[t] (own cols, used in c)
        // and xs[t+1] (used in b)
        if (tid < 256) {
            int r = tid >> 4, c = tid & 15;
            amix[r][128 + c] = us_bf[((size_t)t * 2048 + row0 + r) * 16 + c];
        }
#pragma unroll
        for (int rg = 0; rg < 4; rg++)
            ge[rg] = eps[((size_t)t * 2048 + row0 + quad * 4 + rg) * 128 + w * 16 + l15];
#pragma unroll
        for (int kt = 0; kt < 4; kt++)
            axs[kt] = *(const short8*)&xs_bf[((size_t)(t + 1) * 2048 + row0 + l15) * 128 + kt * 32 + quad * 8];
        __syncthreads();

        // phase b: rec1  r = relu([z|x_{t+1}|u] @ W1 + b1); wave w -> n-tile w
        {
            short8 a[9];
#pragma unroll
            for (int kt = 0; kt < 4; kt++)
                a[kt] = *(const short8*)&amix[l15][kt * 32 + quad * 8];
#pragma unroll
            for (int kt = 4; kt < 8; kt++) a[kt] = axs[kt - 4];
            {
                short8 zz = {0, 0, 0, 0, 0, 0, 0, 0};
                a[8] = (quad < 2) ? *(const short8*)&amix[l15][128 + quad * 8] : zz;
            }
            f32x4 D = {0.f, 0.f, 0.f, 0.f};
#pragma unroll
            for (int kt = 0; kt < 9; kt++)
                D = mfma16(a[kt], r1f[kt], D);
            int col = w * 16 + l15;
#pragma unroll
            for (int rg = 0; rg < 4; rg++) {
                float v = fmaxf(D[rg] + b1s[col], 0.f);
                rb_bf[quad * 4 + rg][col] = f2bf(v);
            }
        }
        __syncthreads();

        // phase c: rec2 mean (nt=w) + logvar (nt=8+w) in-lane -> w into amix
        // cols 144-271; alpha logits (wave 7)
        {
            short8 a2[4];
#pragma unroll
            for (int kt = 0; kt < 4; kt++)
                a2[kt] = *(const short8*)&rb_bf[l15][kt * 32 + quad * 8];
            f32x4 Dm = {0.f, 0.f, 0.f, 0.f}, Dl = {0.f, 0.f, 0.f, 0.f};
#pragma unroll
            for (int kt = 0; kt < 4; kt++) {
                Dm = mfma16(a2[kt], r2f[kt], Dm);
                Dl = mfma16(a2[kt], r2f[4 + kt], Dl);
            }
            int col = w * 16 + l15;
#pragma unroll
            for (int rg = 0; rg < 4; rg++) {
                float mv = Dm[rg] + b2s[col];
                float lv = Dl[rg] + b2s[128 + col];
                float wval = mv + expf(0.5f * lv) * ge[rg];
                amix[quad * 4 + rg][144 + col] = f2bf(wval);
            }
            if (w == 7) {
                short8 az[5];
#pragma unroll
                for (int kt = 0; kt < 4; kt++)
                    az[kt] = *(const short8*)&amix[l15][kt * 32 + quad * 8];
                short8 zz = {0, 0, 0, 0, 0, 0, 0, 0};
                az[4] = (quad < 2) ? *(const short8*)&amix[l15][128 + quad * 8] : zz;
                f32x4 DL = {0.f, 0.f, 0.f, 0.f};
#pragma unroll
                for (int kt = 0; kt < 5; kt++)
                    DL = mfma16(az[kt], alf[kt], DL);
#pragma unroll
                for (int rg = 0; rg < 4; rg++)
                    logits[quad * 4 + rg][l15] = DL[rg];
            }
        }
        __syncthreads();

        // phase d: wave-parallel softmax only (16 rows x 16 i on 256 threads)
        if (tid < 256) {
            int r = tid >> 4, i = tid & 15;
            float x = logits[r][i];
            float m = x;
#pragma unroll
            for (int off = 8; off > 0; off >>= 1)
                m = fmaxf(m, __shfl_xor(m, off, 16));
            float e = expf(x - m);
            float s = e;
#pragma unroll
            for (int off = 8; off > 0; off >>= 1)
                s += __shfl_xor(s, off, 16);
            alph[r][i] = e / s;
        }
        __syncthreads();

        // phase e: mix GEMM. wave w handles i0=2w, i1=2w+1; 8 j-tiles each.
        // #pragma unroll 1 keeps the scheduling window small (128-VGPR cap).
        // kt==0 of i0 comes from LDS (wlds); everything else streams.
        {
            short8 a[9];
#pragma unroll
            for (int kt = 0; kt < 9; kt++)
                a[kt] = *(const short8*)&amix[l15][kt * 32 + quad * 8];
            float a0[4], a1v[4];
#pragma unroll
            for (int rg = 0; rg < 4; rg++) {
                a0[rg] = alph[quad * 4 + rg][i0];
                a1v[rg] = alph[quad * 4 + rg][i1];
            }
#pragma unroll 1
            for (int jt = 0; jt < 8; jt++) {
                f32x4 D0 = {0.f, 0.f, 0.f, 0.f}, D1 = {0.f, 0.f, 0.f, 0.f};
#pragma unroll
                for (int kt = 0; kt < 9; kt++) {
                    short8 b0 = (kt == 0)
                        ? *(const short8*)&wlds[w][jt][lane * 8]
                        : *(const short8*)&wmix_pk[((((size_t)i0 * 8 + jt) * 9 + kt) * 64 + lane) * 8];
                    short8 b1 = *(const short8*)&wmix_pk[((((size_t)i1 * 8 + jt) * 9 + kt) * 64 + lane) * 8];
                    D0 = mfma16(a[kt], b0, D0);
                    D1 = mfma16(a[kt], b1, D1);
                }
#pragma unroll
                for (int rg = 0; rg < 4; rg++)
                    part[w][quad * 4 + rg][jt * 16 + l15] = a0[rg] * D0[rg] + a1v[rg] * D1[rg];
            }
        }
        __syncthreads();

        // phase f: reduce 8 partials -> z_{t+1}; write out + feed back (bf16)
#pragma unroll
        for (int e = 0; e < 4; e++) {
            int idx = tid + e * 512;
            int r = idx >> 7, j = idx & 127;
            float s = 0.f;
#pragma unroll
            for (int ww = 0; ww < 8; ww++) s += part[ww][r][j];
            zs[((size_t)(t + 1) * 2048 + row0 + r) * 128 + j] = s;
            amix[r][j] = f2bf(s);
        }
        __syncthreads();
    }
}

// ---------------------------------------------------------------------------
// fp32 helper GEMMs for the small init-network tail (unchanged)
// ---------------------------------------------------------------------------
template <int RELU>
__global__ __launch_bounds__(256) void gemm_bias_k(
    const float* __restrict__ A, const float* __restrict__ W,
    const float* __restrict__ bias, float* __restrict__ Cout,
    int M, int K, int N)
{
    __shared__ float As[16][68];
    __shared__ float Ws[16][64];
    const int tid = threadIdx.x;
    const int row0 = blockIdx.x * 64;
    const int col0 = blockIdx.y * 64;
    const int tx = tid & 15, ty = tid >> 4;
    float acc[4][4];
#pragma unroll
    for (int a = 0; a < 4; a++)
#pragma unroll
        for (int b = 0; b < 4; b++) acc[a][b] = 0.f;

    for (int kc = 0; kc < K; kc += 16) {
        __syncthreads();
#pragma unroll
        for (int e = 0; e < 4; e++) {
            int idx = tid + e * 256;
            int r = idx >> 4, kk = idx & 15;
            As[kk][r] = A[(size_t)(row0 + r) * K + kc + kk];
        }
#pragma unroll
        for (int e = 0; e < 4; e++) {
            int idx = tid + e * 256;
            int kk = idx >> 6, jj = idx & 63;
            Ws[kk][jj] = W[(kc + kk) * N + col0 + jj];
        }
        __syncthreads();
#pragma unroll
        for (int kk = 0; kk < 16; kk++) {
            const float4 a4 = *(const float4*)&As[kk][ty * 4];
            const float4 w4 = *(const float4*)&Ws[kk][tx * 4];
            const float av[4] = {a4.x, a4.y, a4.z, a4.w};
            const float wv2[4] = {w4.x, w4.y, w4.z, w4.w};
#pragma unroll
            for (int r = 0; r < 4; r++)
#pragma unroll
                for (int j = 0; j < 4; j++) acc[r][j] += av[r] * wv2[j];
        }
    }
#pragma unroll
    for (int r = 0; r < 4; r++)
#pragma unroll
        for (int j = 0; j < 4; j++) {
            int gr = row0 + ty * 4 + r, gc = col0 + tx * 4 + j;
            float v = acc[r][j] + bias[gc];
            if (RELU) v = fmaxf(v, 0.f);
            Cout[(size_t)gr * N + gc] = v;
        }
}

__global__ __launch_bounds__(256) void gemm_meanvar_k(
    const float* __restrict__ A, const float* __restrict__ W,
    const float* __restrict__ bias, const float* __restrict__ eps,
    float* __restrict__ out)
{
    __shared__ float As[16][36];
    __shared__ float Ws[16][128];
    const int tid = threadIdx.x;
    const int row0 = blockIdx.x * 32;
    const int j0 = blockIdx.y * 64;
    const int tjx = tid & 31;
    const int trg = tid >> 5;
    float am[4][2], al[4][2];
#pragma unroll
    for (int a = 0; a < 4; a++) { am[a][0] = am[a][1] = 0.f; al[a][0] = al[a][1] = 0.f; }

    for (int kc = 0; kc < 128; kc += 16) {
        __syncthreads();
#pragma unroll
        for (int e = 0; e < 2; e++) {
            int idx = tid + e * 256;
            int r = idx >> 4, kk = idx & 15;
            As[kk][r] = A[(row0 + r) * 128 + kc + kk];
        }
#pragma unroll
        for (int e = 0; e < 2; e++) {
            int idx = tid + e * 256;
            int lin = idx * 4;
            int kk = lin >> 7, cc = lin & 127;
            int half = cc >> 6, jj = cc & 63;
            *(float4*)&Ws[kk][half * 64 + jj] =
                *(const float4*)(W + (kc + kk) * 256 + half * 128 + j0 + jj);
        }
        __syncthreads();
#pragma unroll
        for (int kk = 0; kk < 16; kk++) {
            const float4 a4 = *(const float4*)&As[kk][trg * 4];
            const float2 wm = *(const float2*)&Ws[kk][2 * tjx];
            const float2 wl = *(const float2*)&Ws[kk][64 + 2 * tjx];
            const float av[4] = {a4.x, a4.y, a4.z, a4.w};
#pragma unroll
            for (int rr = 0; rr < 4; rr++) {
                am[rr][0] += av[rr] * wm.x; am[rr][1] += av[rr] * wm.y;
                al[rr][0] += av[rr] * wl.x; al[rr][1] += av[rr] * wl.y;
            }
        }
    }
#pragma unroll
    for (int rr = 0; rr < 4; rr++)
#pragma unroll
        for (int jj = 0; jj < 2; jj++) {
            int r = row0 + trg * 4 + rr;
            int j = j0 + 2 * tjx + jj;
            float m = am[rr][jj] + bias[j];
            float l = al[rr][jj] + bias[128 + j];
            out[r * 128 + j] = m + expf(0.5f * l) * eps[r * 128 + j];
        }
}

// ---------------------------------------------------------------------------
// Fused 2-layer MLP for x_rec (fp32, unchanged)
// ---------------------------------------------------------------------------
__global__ __launch_bounds__(256) void mlp2_k(
    const float* __restrict__ Z, const float* __restrict__ W1,
    const float* __restrict__ b1, const float* __restrict__ W2,
    const float* __restrict__ b2, float* __restrict__ out)
{
    __shared__ float Zs[32][132];
    __shared__ float Hs[32][132];
    __shared__ float Ws[16][128];
    const int tid = threadIdx.x;
    const int row0 = blockIdx.x * 32;
    const int tx = tid & 31;
    const int ty = tid >> 5;

#pragma unroll
    for (int e = 0; e < 4; e++) {
        int idx = tid + e * 256;
        int lin = idx * 4;
        int r = lin >> 7, k = lin & 127;
        *(float4*)&Zs[r][k] = *(const float4*)(Z + (size_t)(row0 + r) * 128 + k);
    }

    float acc[4][4];
#pragma unroll
    for (int a = 0; a < 4; a++)
#pragma unroll
        for (int b = 0; b < 4; b++) acc[a][b] = 0.f;

    for (int kc = 0; kc < 128; kc += 16) {
        __syncthreads();
#pragma unroll
        for (int e = 0; e < 2; e++) {
            int idx = tid + e * 256;
            int lin = idx * 4;
            int kk = lin >> 7, j = lin & 127;
            *(float4*)&Ws[kk][j] = *(const float4*)(W1 + (kc + kk) * 128 + j);
        }
        __syncthreads();
#pragma unroll
        for (int kk = 0; kk < 16; kk++) {
            float av[4];
#pragma unroll
            for (int rr = 0; rr < 4; rr++) av[rr] = Zs[ty * 4 + rr][kc + kk];
            const float4 w4 = *(const float4*)&Ws[kk][tx * 4];
            const float wv2[4] = {w4.x, w4.y, w4.z, w4.w};
#pragma unroll
            for (int r = 0; r < 4; r++)
#pragma unroll
                for (int j = 0; j < 4; j++) acc[r][j] += av[r] * wv2[j];
        }
    }
#pragma unroll
    for (int rr = 0; rr < 4; rr++) {
        float4 hv;
        hv.x = fmaxf(acc[rr][0] + b1[tx * 4 + 0], 0.f);
        hv.y = fmaxf(acc[rr][1] + b1[tx * 4 + 1], 0.f);
        hv.z = fmaxf(acc[rr][2] + b1[tx * 4 + 2], 0.f);
        hv.w = fmaxf(acc[rr][3] + b1[tx * 4 + 3], 0.f);
        *(float4*)&Hs[ty * 4 + rr][tx * 4] = hv;
    }
#pragma unroll
    for (int a = 0; a < 4; a++)
#pragma unroll
        for (int b = 0; b < 4; b++) acc[a][b] = 0.f;

    for (int kc = 0; kc < 128; kc += 16) {
        __syncthreads();
#pragma unroll
        for (int e = 0; e < 2; e++) {
            int idx = tid + e * 256;
            int lin = idx * 4;
            int kk = lin >> 7, j = lin & 127;
            *(float4*)&Ws[kk][j] = *(const float4*)(W2 + (kc + kk) * 128 + j);
        }
        __syncthreads();
#pragma unroll
        for (int kk = 0; kk < 16; kk++) {
            float av[4];
#pragma unroll
            for (int rr = 0; rr < 4; rr++) av[rr] = Hs[ty * 4 + rr][kc + kk];
            const float4 w4 = *(const float4*)&Ws[kk][tx * 4];
            const float wv2[4] = {w4.x, w4.y, w4.z, w4.w};
#pragma unroll
            for (int r = 0; r < 4; r++)
#pragma unroll
                for (int j = 0; j < 4; j++) acc[r][j] += av[r] * wv2[j];
        }
    }
#pragma unroll
    for (int rr = 0; rr < 4; rr++) {
        float4 ov;
        ov.x = acc[rr][0] + b2[tx * 4 + 0];
        ov.y = acc[rr][1] + b2[tx * 4 + 1];
        ov.z = acc[rr][2] + b2[tx * 4 + 2];
        ov.w = acc[rr][3] + b2[tx * 4 + 3];
        *(float4*)(out + (size_t)(row0 + ty * 4 + rr) * 128 + tx * 4) = ov;
    }
}

// ---------------------------------------------------------------------------
extern "C" void kernel_launch(void* const* d_in, const int* in_sizes, int n_in,
                              void* d_out, int out_size, void* d_ws, size_t ws_size,
                              hipStream_t stream)
{
    (void)in_sizes; (void)n_in; (void)out_size; (void)ws_size;
    const float* xs       = (const float*)d_in[0];
    const float* us       = (const float*)d_in[1];
    const float* eps1     = (const float*)d_in[2];
    const float* eps      = (const float*)d_in[3];
    const float* lstm_Wx  = (const float*)d_in[4];
    const float* lstm_Wh  = (const float*)d_in[5];
    const float* lstm_b   = (const float*)d_in[6];
    const float* init_W1  = (const float*)d_in[7];
    const float* init_b1  = (const float*)d_in[8];
    const float* init_W2  = (const float*)d_in[9];
    const float* init_b2  = (const float*)d_in[10];
    const float* trans_W1 = (const float*)d_in[11];
    const float* trans_b1 = (const float*)d_in[12];
    const float* trans_W2 = (const float*)d_in[13];
    const float* trans_b2 = (const float*)d_in[14];
    const float* obs_W1   = (const float*)d_in[15];
    const float* obs_b1   = (const float*)d_in[16];
    const float* obs_W2   = (const float*)d_in[17];
    const float* obs_b2   = (const float*)d_in[18];
    const float* rec_W1   = (const float*)d_in[19];
    const float* rec_b1   = (const float*)d_in[20];
    const float* rec_W2   = (const float*)d_in[21];
    const float* rec_b2   = (const float*)d_in[22];
    const float* alpha_W  = (const float*)d_in[23];
    const float* Amat     = (const float*)d_in[24];
    const float* Bmat     = (const float*)d_in[25];
    const float* Cmat     = (const float*)d_in[26];

    float* out  = (float*)d_out;
    float* zs   = out;                           // (64*2048, 128)
    float* xrec = out + (size_t)TT * BB * LATN;  // (63*2048, 128)

    // workspace layout (bytes)
    char* ws = (char*)d_ws;
    unsigned short* xs_bf   = (unsigned short*)(ws);                    // 33,554,432 B
    unsigned short* us_bf   = (unsigned short*)(ws + 33554432);         //  4,194,304 B
    unsigned short* lstm_pk = (unsigned short*)(ws + 37748736);         //    262,144 B
    unsigned short* rec1_pk = (unsigned short*)(ws + 38010880);         //     73,728 B
    unsigned short* rec2_pk = (unsigned short*)(ws + 38084608);         //     65,536 B
    unsigned short* alpha_pk= (unsigned short*)(ws + 38150144);         //      5,120 B
    unsigned short* wmix_pk = (unsigned short*)(ws + 38155264);         //  1,179,648 B
    float* hlast            = (float*)(ws + 39334912);                  //  1,048,576 B
    float* hidb             = (float*)(ws + 40383488);
    float* w1b              = (float*)(ws + 41432064);
    float* rbg              = (float*)(ws + 42480640);                  // ends 43,529,216

    // ---- prep ----
    cvt_bf4_k<<<16384, 256, 0, stream>>>(xs, xs_bf, 4194304);
    cvt_bf4_k<<<2048, 256, 0, stream>>>(us, us_bf, 524288);
    pack_lstm_k<<<64, 256, 0, stream>>>(lstm_Wx, lstm_Wh, lstm_pk);
    pack_b_k<<<18, 256, 0, stream>>>(rec_W1, rec1_pk, 272, 128, 9);
    pack_b_k<<<16, 256, 0, stream>>>(rec_W2, rec2_pk, 128, 256, 4);
    pack_b_k<<<2, 256, 0, stream>>>(alpha_W, alpha_pk, 144, 16, 5);
    pack_wmix_k<<<288, 256, 0, stream>>>(Amat, Bmat, Cmat, wmix_pk);

    // ---- LSTM (persistent, weight-resident) ----
    lstm_k<<<128, 512, 0, stream>>>(xs_bf, lstm_pk, lstm_b, hlast);

    // ---- init-network tail + initial transition (fp32) ----
    gemm_bias_k<1><<<dim3(32, 2), 256, 0, stream>>>(hlast, init_W1, init_b1, hidb, BB, 128, 128);
    gemm_meanvar_k<<<dim3(64, 2), 256, 0, stream>>>(hidb, init_W2, init_b2, eps1, w1b);
    gemm_bias_k<1><<<dim3(32, 2), 256, 0, stream>>>(w1b, trans_W1, trans_b1, rbg, BB, 128, 128);
    gemm_bias_k<0><<<dim3(32, 2), 256, 0, stream>>>(rbg, trans_W2, trans_b2, zs, BB, 128, 128);

    // ---- DVBF scan (round-3 structure + in-lane w-comp + small LDS persist) ----
    scan_k<<<128, 512, 0, stream>>>(xs_bf, us_bf, eps,
                                    rec1_pk, rec_b1, rec2_pk, rec_b2,
                                    alpha_pk, wmix_pk, zs);

    // ---- x_rec = obs_fn(zs[0..62]) ----
    mlp2_k<<<dim3((TT - 1) * BB / 32), 256, 0, stream>>>(
        zs, obs_W1, obs_b1, obs_W2, obs_b2, xrec);
}